// Round 4
// baseline (478.014 us; speedup 1.0000x reference)
//
#include <hip/hip_runtime.h>
#include <hip/hip_bf16.h>

#define N_NODES_C 87381

typedef __attribute__((ext_vector_type(8))) short bf16x8;
typedef __attribute__((ext_vector_type(4))) float f32x4;

__device__ __forceinline__ ushort f2bf(float f) {
  union { float f; unsigned u; } v; v.f = f;
  unsigned u = v.u;
  return (ushort)((u + 0x7FFFu + ((u >> 16) & 1u)) >> 16);
}

__device__ __forceinline__ float fsig(float x) {
  return __builtin_amdgcn_rcpf(1.0f + __expf(-x));
}
__device__ __forceinline__ float ftnh(float x) {
  float e = __expf(2.0f * x);
  return 1.0f - 2.0f * __builtin_amdgcn_rcpf(e + 1.0f);
}

__device__ __forceinline__ f32x4 MF(bf16x8 a, bf16x8 b, f32x4 c) {
  return __builtin_amdgcn_mfma_f32_16x16x32_bf16(a, b, c, 0, 0, 0);
}

// Repack (unchanged from round 3):
//  [0, 262144)      : gate-weight B-fragments, wave-slice layout
//  [262144, 393216) : emb -> bf16
//  [393216, 425984) : lin_w -> per-lane B-fragments
__global__ __launch_bounds__(256) void repack_all(
    const float* __restrict__ wihf, const float* __restrict__ whhf,
    const float* __restrict__ wihb, const float* __restrict__ whhb,
    const float* __restrict__ emb, const float* __restrict__ linw,
    ushort* __restrict__ wrep, ushort* __restrict__ emb_bf,
    ushort* __restrict__ lwrep) {
  int i = blockIdx.x * 256 + threadIdx.x;
  if (i < 262144) {
    int j = i & 7;
    int fr = (i >> 3) & 15;
    int lane = (i >> 7) & 63;
    int w = (i >> 13) & 7;
    int m = (i >> 16) & 1;
    int d = (i >> 17) & 1;
    int nt = fr >> 2, kk = fr & 3;
    int pcol = w * 64 + nt * 16 + (lane & 15);
    int gate = (pcol >> 4) & 3;
    int h = ((pcol >> 6) << 4) | (pcol & 15);
    int k = kk * 32 + (lane >> 4) * 8 + j;
    const float* src = d ? (m ? whhb : wihb) : (m ? whhf : wihf);
    wrep[i] = f2bf(src[(gate * 128 + h) * 128 + k]);
  } else if (i < 393216) {
    int r = i - 262144;
    emb_bf[r] = f2bf(emb[r]);
  } else if (i < 425984) {
    int r = i - 393216;
    int j = r & 7;
    int kk = (r >> 3) & 7;
    int l = (r >> 6) & 63;
    int w = (r >> 12) & 7;
    int e = w * 16 + (l & 15);
    int k = kk * 32 + (l >> 4) * 8 + j;
    lwrep[r] = f2bf(linw[e * 256 + k]);
  }
}

// 8 waves, wave w owns hidden slice [16w,16w+16) (gates lane-local in C).
// Input-side GEMMs are OUT of the recurrence: x-gates cached in caccX
// (reused at t=0 and t=T-1); child gates for step t+1 computed during
// step t from per-lane global-gathered A-fragments (no LDS staging).
// Recurrence step: 4 ds_read (h) -> 16 h-MFMAs -> elementwise -> h-write.
template <int NG>
__global__ __launch_bounds__(512, 2) void tree_scan2(
    const int* __restrict__ labels, const ushort* __restrict__ emb_bf,
    const ushort* __restrict__ wrep,
    const float* __restrict__ bihf, const float* __restrict__ bhhf,
    const float* __restrict__ bihb, const float* __restrict__ bhhb,
    const ushort* __restrict__ lwrep, const float* __restrict__ linb,
    ushort* __restrict__ enc, float* __restrict__ out,
    int start, int count, int T, int ngroups) {
  __shared__ __align__(16) ushort sH[2][2048];    // h dbuf, XOR-swizzled
  __shared__ __align__(16) ushort sHF[NG][2048];  // dir0 final h per group

  const int tid = threadIdx.x;
  const int w = tid >> 6;
  const int l = tid & 63;
  const int hlo = l & 15;
  const int lg = l >> 4;
  const int r0 = lg * 4;
  const int hcol = w * 16 + hlo;
  const int arow = hlo;
  const int axswz = (arow & 7) << 3;
  const int k0 = lg * 8;
  const int g0 = blockIdx.x * NG;
  const int cstart = start + count;
  const float lb = linb[hcol];

  for (int dir = 0; dir < 2; ++dir) {
    // weight B-fragments -> regs (once per dir)
    bf16x8 wih[16], whh[16];
    {
      const ushort* p0 = wrep + (((dir * 2 + 0) * 8 + w) << 13) + l * 128;
      const ushort* p1 = wrep + (((dir * 2 + 1) * 8 + w) << 13) + l * 128;
#pragma unroll
      for (int f = 0; f < 16; ++f) {
        wih[f] = *(const bf16x8*)(p0 + f * 8);
        whh[f] = *(const bf16x8*)(p1 + f * 8);
      }
    }
    const float* bih = dir ? bihb : bihf;
    const float* bhh = dir ? bhhb : bhhf;
    float bs[4];
#pragma unroll
    for (int nt = 0; nt < 4; ++nt) bs[nt] = bih[nt * 128 + hcol] + bhh[nt * 128 + hcol];

    for (int g = 0; g < NG; ++g) {
      const int gg = g0 + g;
      if (gg >= ngroups) break;
      const int node0 = gg * 16;
      int n = node0 + hlo;
      if (n >= count) n = count - 1;
      const int lab = labels[start + n];

      // prologue: x A-frags (per-lane global gather) -> caccX = bias + x@Wih^T
      f32x4 caccX[4];
      {
        const ushort* xr = emb_bf + lab * 128 + k0;
        bf16x8 ax[4];
#pragma unroll
        for (int kk = 0; kk < 4; ++kk) ax[kk] = *(const bf16x8*)(xr + kk * 32);
#pragma unroll
        for (int nt = 0; nt < 4; ++nt) {
          f32x4 z = {bs[nt], bs[nt], bs[nt], bs[nt]};
          caccX[nt] = z;
        }
#pragma unroll
        for (int kk = 0; kk < 4; ++kk)
#pragma unroll
          for (int nt = 0; nt < 4; ++nt)
            caccX[nt] = MF(ax[kk], wih[nt * 4 + kk], caccX[nt]);
      }

      f32x4 cin[4];
      bf16x8 ach[4];
      if (T > 2) {  // preload A-frags for input_1 (child)
        int ci = dir ? (T - 3) : 0;
        const ushort* cr = enc + ((size_t)(cstart + n * 4 + ci)) * 128 + k0;
#pragma unroll
        for (int kk = 0; kk < 4; ++kk) ach[kk] = *(const bf16x8*)(cr + kk * 32);
      }

      float c_st[4], hn[4];

      for (int t = 0; t < T; ++t) {
        f32x4 a4[4];
        const bool useX = (t == 0) || (t == T - 1);
#pragma unroll
        for (int nt = 0; nt < 4; ++nt) a4[nt] = useX ? caccX[nt] : cin[nt];

        if (t > 0) {  // h-side MFMAs (skipped at t=0: h=0)
          bf16x8 ah[4];
#pragma unroll
          for (int kk = 0; kk < 4; ++kk)
            ah[kk] = *(const bf16x8*)(sH[(t + 1) & 1] + arow * 128 +
                                      ((kk * 32 + k0) ^ axswz));
#pragma unroll
          for (int kk = 0; kk < 4; ++kk)
#pragma unroll
            for (int nt = 0; nt < 4; ++nt)
              a4[nt] = MF(ah[kk], whh[nt * 4 + kk], a4[nt]);
        }

        if (T > 2) {
          if (t + 1 <= T - 2) {  // gates for input_{t+1} (independent side-GEMM)
#pragma unroll
            for (int nt = 0; nt < 4; ++nt) {
              f32x4 z = {bs[nt], bs[nt], bs[nt], bs[nt]};
              cin[nt] = z;
            }
#pragma unroll
            for (int kk = 0; kk < 4; ++kk)
#pragma unroll
              for (int nt = 0; nt < 4; ++nt)
                cin[nt] = MF(ach[kk], wih[nt * 4 + kk], cin[nt]);
          }
          if (t + 2 <= T - 2) {  // issue A-loads for input_{t+2}
            int ci = dir ? (T - 4 - t) : (t + 1);
            const ushort* cr = enc + ((size_t)(cstart + n * 4 + ci)) * 128 + k0;
#pragma unroll
            for (int kk = 0; kk < 4; ++kk) ach[kk] = *(const bf16x8*)(cr + kk * 32);
          }
        }

        // lane-local LSTM elementwise (gates i,f,g,o = a4[0..3])
#pragma unroll
        for (int rg = 0; rg < 4; ++rg) {
          float iv = fsig(a4[0][rg]);
          float fv = fsig(a4[1][rg]);
          float gv = ftnh(a4[2][rg]);
          float ov = fsig(a4[3][rg]);
          float c = (t == 0) ? (iv * gv) : (fv * c_st[rg] + iv * gv);
          c_st[rg] = c;
          hn[rg] = ov * ftnh(c);
        }

        // h write (swizzled)
        if (t < T - 1) {
#pragma unroll
          for (int rg = 0; rg < 4; ++rg) {
            int rr = r0 + rg;
            sH[t & 1][rr * 128 + (hcol ^ ((rr & 7) << 3))] = f2bf(hn[rg]);
          }
        } else if (dir == 0) {
#pragma unroll
          for (int rg = 0; rg < 4; ++rg) {
            int rr = r0 + rg;
            sHF[g][rr * 128 + (hcol ^ ((rr & 7) << 3))] = f2bf(hn[rg]);
          }
        } else {
#pragma unroll
          for (int rg = 0; rg < 4; ++rg) {
            int rr = r0 + rg;
            sH[1][rr * 128 + (hcol ^ ((rr & 7) << 3))] = f2bf(hn[rg]);
          }
        }
        __syncthreads();
      }

      if (dir == 1) {
        // fused head: out = tanh([hf,hb] @ lin_w^T + lin_b)
        bf16x8 lw[8];
        const ushort* lp = lwrep + (w * 64 + l) * 64;
#pragma unroll
        for (int kk = 0; kk < 8; ++kk) lw[kk] = *(const bf16x8*)(lp + kk * 8);
        f32x4 a2 = {lb, lb, lb, lb};
#pragma unroll
        for (int kk = 0; kk < 4; ++kk) {
          bf16x8 hf = *(const bf16x8*)(sHF[g] + arow * 128 + ((kk * 32 + k0) ^ axswz));
          a2 = MF(hf, lw[kk], a2);
        }
#pragma unroll
        for (int kk = 0; kk < 4; ++kk) {
          bf16x8 hb = *(const bf16x8*)(sH[1] + arow * 128 + ((kk * 32 + k0) ^ axswz));
          a2 = MF(hb, lw[4 + kk], a2);
        }
#pragma unroll
        for (int rg = 0; rg < 4; ++rg) {
          int nn = node0 + r0 + rg;
          if (nn < count) {
            float val = ftnh(a2[rg]);
            enc[(size_t)(start + nn) * 128 + hcol] = f2bf(val);
            if (start + nn == 0) out[hcol] = val;
          }
        }
      }
    }
  }
}

extern "C" void kernel_launch(void* const* d_in, const int* in_sizes, int n_in,
                              void* d_out, int out_size, void* d_ws, size_t ws_size,
                              hipStream_t stream) {
  const int* labels = (const int*)d_in[0];
  const float* emb = (const float*)d_in[1];
  const float* w_ih_f = (const float*)d_in[2];
  const float* w_hh_f = (const float*)d_in[3];
  const float* b_ih_f = (const float*)d_in[4];
  const float* b_hh_f = (const float*)d_in[5];
  const float* w_ih_b = (const float*)d_in[6];
  const float* w_hh_b = (const float*)d_in[7];
  const float* b_ih_b = (const float*)d_in[8];
  const float* b_hh_b = (const float*)d_in[9];
  const float* lin_w = (const float*)d_in[10];
  const float* lin_b = (const float*)d_in[11];
  float* out = (float*)d_out;

  ushort* enc = (ushort*)d_ws;                       // 87381*128 bf16
  ushort* wrep = enc + (size_t)N_NODES_C * 128;      // 262144
  ushort* emb_bf = wrep + 262144;                    // 131072
  ushort* lwrep = emb_bf + 131072;                   // 32768

  repack_all<<<1664, 256, 0, stream>>>(w_ih_f, w_hh_f, w_ih_b, w_hh_b, emb,
                                       lin_w, wrep, emb_bf, lwrep);

  for (int level = 8; level >= 0; --level) {
    const int start = ((1 << (2 * level)) - 1) / 3;
    const int count = 1 << (2 * level);
    const int T = (level == 8) ? 2 : 6;
    const int ngroups = (count + 15) >> 4;
    const int ng = (level == 8) ? 16 : (level == 7) ? 4 : 1;
    const int grid = (ngroups + ng - 1) / ng;
    if (ng == 16)
      tree_scan2<16><<<grid, 512, 0, stream>>>(labels, emb_bf, wrep, b_ih_f, b_hh_f,
                                               b_ih_b, b_hh_b, lwrep, lin_b, enc,
                                               out, start, count, T, ngroups);
    else if (ng == 4)
      tree_scan2<4><<<grid, 512, 0, stream>>>(labels, emb_bf, wrep, b_ih_f, b_hh_f,
                                              b_ih_b, b_hh_b, lwrep, lin_b, enc,
                                              out, start, count, T, ngroups);
    else
      tree_scan2<1><<<grid, 512, 0, stream>>>(labels, emb_bf, wrep, b_ih_f, b_hh_f,
                                              b_ih_b, b_hh_b, lwrep, lin_b, enc,
                                              out, start, count, T, ngroups);
  }
}

// Round 5
// 353.240 us; speedup vs baseline: 1.3532x; 1.3532x over previous
//
#include <hip/hip_runtime.h>
#include <hip/hip_bf16.h>

typedef __attribute__((ext_vector_type(8))) short bf16x8;
typedef __attribute__((ext_vector_type(4))) float f32x4;

__device__ __forceinline__ ushort f2bf(float f) {
  union { float f; unsigned u; } v; v.f = f;
  unsigned u = v.u;
  return (ushort)((u + 0x7FFFu + ((u >> 16) & 1u)) >> 16);
}

__device__ __forceinline__ float fsig(float x) {
  return __builtin_amdgcn_rcpf(1.0f + __expf(-x));
}
__device__ __forceinline__ float ftnh(float x) {
  float e = __expf(2.0f * x);
  return 1.0f - 2.0f * __builtin_amdgcn_rcpf(e + 1.0f);
}

__device__ __forceinline__ f32x4 MF(bf16x8 a, bf16x8 b, f32x4 c) {
  return __builtin_amdgcn_mfma_f32_16x16x32_bf16(a, b, c, 0, 0, 0);
}

// Repack:
//  [0, 262144)      : gate-weight B-fragments, wave-slice layout
//  [262144, 393216) : emb -> bf16
//  [393216, 425984) : lin_w -> per-lane B-fragments
__global__ __launch_bounds__(256) void repack_all(
    const float* __restrict__ wihf, const float* __restrict__ whhf,
    const float* __restrict__ wihb, const float* __restrict__ whhb,
    const float* __restrict__ emb, const float* __restrict__ linw,
    ushort* __restrict__ wrep, ushort* __restrict__ emb_bf,
    ushort* __restrict__ lwrep) {
  int i = blockIdx.x * 256 + threadIdx.x;
  if (i < 262144) {
    int j = i & 7;
    int fr = (i >> 3) & 15;
    int lane = (i >> 7) & 63;
    int w = (i >> 13) & 7;
    int m = (i >> 16) & 1;
    int d = (i >> 17) & 1;
    int nt = fr >> 2, kk = fr & 3;
    int pcol = w * 64 + nt * 16 + (lane & 15);
    int gate = (pcol >> 4) & 3;
    int h = ((pcol >> 6) << 4) | (pcol & 15);
    int k = kk * 32 + (lane >> 4) * 8 + j;
    const float* src = d ? (m ? whhb : wihb) : (m ? whhf : wihf);
    wrep[i] = f2bf(src[(gate * 128 + h) * 128 + k]);
  } else if (i < 393216) {
    int r = i - 262144;
    emb_bf[r] = f2bf(emb[r]);
  } else if (i < 425984) {
    int r = i - 393216;
    int j = r & 7;
    int kk = (r >> 3) & 7;
    int l = (r >> 6) & 63;
    int w = (r >> 12) & 7;
    int e = w * 16 + (l & 15);
    int k = kk * 32 + (l >> 4) * 8 + j;
    lwrep[r] = f2bf(linw[e * 256 + k]);
  }
}

// Generic level scan. 8 waves, wave w owns hidden slice [16w,16w+16).
// x source: emb_bf[xlab ? xlab[n] : n].
// child row t: csrc[clab ? clab[cbase+n*4+ci] : (cbase+n*4+ci)].
// head result -> dst + n*128 (+ out[] if nn==outnode).
// Input-side GEMMs pipelined out of the h-recurrence (cin one step ahead,
// ach A-frags prefetched two steps ahead).
template <int NG>
__global__ __launch_bounds__(512, 1) void tree_scan3(
    const int* __restrict__ xlab, const ushort* __restrict__ emb_bf,
    const ushort* __restrict__ wrep,
    const float* __restrict__ bihf, const float* __restrict__ bhhf,
    const float* __restrict__ bihb, const float* __restrict__ bhhb,
    const ushort* __restrict__ lwrep, const float* __restrict__ linb,
    const ushort* __restrict__ csrc, const int* __restrict__ clab, int cbase,
    ushort* __restrict__ dst, float* __restrict__ out, int outnode,
    int count, int T, int ngroups) {
  __shared__ __align__(16) ushort sH[2][2048];    // h dbuf, XOR-swizzled
  __shared__ __align__(16) ushort sHF[NG][2048];  // dir0 final h per group

  const int tid = threadIdx.x;
  const int w = tid >> 6;
  const int l = tid & 63;
  const int hlo = l & 15;
  const int lg = l >> 4;
  const int r0 = lg * 4;
  const int hcol = w * 16 + hlo;
  const int arow = hlo;
  const int axswz = (arow & 7) << 3;
  const int k0 = lg * 8;
  const int g0 = blockIdx.x * NG;
  const float lb = linb[hcol];

  for (int dir = 0; dir < 2; ++dir) {
    // weight B-fragments -> regs (once per dir)
    bf16x8 wih[16], whh[16];
    {
      const ushort* p0 = wrep + (((dir * 2 + 0) * 8 + w) << 13) + l * 128;
      const ushort* p1 = wrep + (((dir * 2 + 1) * 8 + w) << 13) + l * 128;
#pragma unroll
      for (int f = 0; f < 16; ++f) {
        wih[f] = *(const bf16x8*)(p0 + f * 8);
        whh[f] = *(const bf16x8*)(p1 + f * 8);
      }
    }
    const float* bih = dir ? bihb : bihf;
    const float* bhh = dir ? bhhb : bhhf;
    float bs[4];
#pragma unroll
    for (int nt = 0; nt < 4; ++nt) bs[nt] = bih[nt * 128 + hcol] + bhh[nt * 128 + hcol];

    for (int g = 0; g < NG; ++g) {
      const int gg = g0 + g;
      if (gg >= ngroups) break;
      const int node0 = gg * 16;
      int n = node0 + hlo;
      if (n >= count) n = count - 1;

      // prologue: x A-frags -> caccX = bias + x@Wih^T (reused at t=0, t=T-1)
      f32x4 caccX[4];
      {
        const int xi = xlab ? xlab[n] : n;
        const ushort* xr = emb_bf + (size_t)xi * 128 + k0;
        bf16x8 ax[4];
#pragma unroll
        for (int kk = 0; kk < 4; ++kk) ax[kk] = *(const bf16x8*)(xr + kk * 32);
#pragma unroll
        for (int nt = 0; nt < 4; ++nt) {
          f32x4 z = {bs[nt], bs[nt], bs[nt], bs[nt]};
          caccX[nt] = z;
        }
#pragma unroll
        for (int kk = 0; kk < 4; ++kk)
#pragma unroll
          for (int nt = 0; nt < 4; ++nt)
            caccX[nt] = MF(ax[kk], wih[nt * 4 + kk], caccX[nt]);
      }

      int labs[4];
      f32x4 cin[4];
      bf16x8 ach[4];
      if (T > 2) {
        if (clab) {
#pragma unroll
          for (int ci = 0; ci < 4; ++ci) labs[ci] = clab[cbase + n * 4 + ci];
        }
        const int ci0 = dir ? (T - 3) : 0;
        const int row = clab ? labs[ci0] : (cbase + n * 4 + ci0);
        const ushort* cr = csrc + (size_t)row * 128 + k0;
#pragma unroll
        for (int kk = 0; kk < 4; ++kk) ach[kk] = *(const bf16x8*)(cr + kk * 32);
      }

      float c_st[4], hn[4];

      for (int t = 0; t < T; ++t) {
        f32x4 a4[4];
        const bool useX = (t == 0) || (t == T - 1);
#pragma unroll
        for (int nt = 0; nt < 4; ++nt) a4[nt] = useX ? caccX[nt] : cin[nt];

        if (t > 0) {  // h-side MFMAs (h0 = 0)
          bf16x8 ah[4];
#pragma unroll
          for (int kk = 0; kk < 4; ++kk)
            ah[kk] = *(const bf16x8*)(sH[(t + 1) & 1] + arow * 128 +
                                      ((kk * 32 + k0) ^ axswz));
#pragma unroll
          for (int kk = 0; kk < 4; ++kk)
#pragma unroll
            for (int nt = 0; nt < 4; ++nt)
              a4[nt] = MF(ah[kk], whh[nt * 4 + kk], a4[nt]);
        }

        if (T > 2) {
          if (t + 1 <= T - 2) {  // input gates for step t+1 (shadow GEMM)
#pragma unroll
            for (int nt = 0; nt < 4; ++nt) {
              f32x4 z = {bs[nt], bs[nt], bs[nt], bs[nt]};
              cin[nt] = z;
            }
#pragma unroll
            for (int kk = 0; kk < 4; ++kk)
#pragma unroll
              for (int nt = 0; nt < 4; ++nt)
                cin[nt] = MF(ach[kk], wih[nt * 4 + kk], cin[nt]);
          }
          if (t + 2 <= T - 2) {  // prefetch A-frags for step t+2
            const int ci = dir ? (T - 4 - t) : (t + 1);
            const int row = clab ? labs[ci] : (cbase + n * 4 + ci);
            const ushort* cr = csrc + (size_t)row * 128 + k0;
#pragma unroll
            for (int kk = 0; kk < 4; ++kk) ach[kk] = *(const bf16x8*)(cr + kk * 32);
          }
        }

        // lane-local LSTM elementwise (gates i,f,g,o = a4[0..3])
#pragma unroll
        for (int rg = 0; rg < 4; ++rg) {
          float iv = fsig(a4[0][rg]);
          float fv = fsig(a4[1][rg]);
          float gv = ftnh(a4[2][rg]);
          float ov = fsig(a4[3][rg]);
          float c = (t == 0) ? (iv * gv) : (fv * c_st[rg] + iv * gv);
          c_st[rg] = c;
          hn[rg] = ov * ftnh(c);
        }

        // h write (swizzled)
        if (t < T - 1) {
#pragma unroll
          for (int rg = 0; rg < 4; ++rg) {
            int rr = r0 + rg;
            sH[t & 1][rr * 128 + (hcol ^ ((rr & 7) << 3))] = f2bf(hn[rg]);
          }
        } else if (dir == 0) {
#pragma unroll
          for (int rg = 0; rg < 4; ++rg) {
            int rr = r0 + rg;
            sHF[g][rr * 128 + (hcol ^ ((rr & 7) << 3))] = f2bf(hn[rg]);
          }
        } else {
#pragma unroll
          for (int rg = 0; rg < 4; ++rg) {
            int rr = r0 + rg;
            sH[1][rr * 128 + (hcol ^ ((rr & 7) << 3))] = f2bf(hn[rg]);
          }
        }
        __syncthreads();
      }

      if (dir == 1) {
        // fused head: tanh([hf,hb] @ lin_w^T + lin_b)
        bf16x8 lw[8];
        const ushort* lp = lwrep + (w * 64 + l) * 64;
#pragma unroll
        for (int kk = 0; kk < 8; ++kk) lw[kk] = *(const bf16x8*)(lp + kk * 8);
        f32x4 a2 = {lb, lb, lb, lb};
#pragma unroll
        for (int kk = 0; kk < 4; ++kk) {
          bf16x8 hf = *(const bf16x8*)(sHF[g] + arow * 128 + ((kk * 32 + k0) ^ axswz));
          a2 = MF(hf, lw[kk], a2);
        }
#pragma unroll
        for (int kk = 0; kk < 4; ++kk) {
          bf16x8 hb = *(const bf16x8*)(sH[1] + arow * 128 + ((kk * 32 + k0) ^ axswz));
          a2 = MF(hb, lw[4 + kk], a2);
        }
#pragma unroll
        for (int rg = 0; rg < 4; ++rg) {
          int nn = node0 + r0 + rg;
          if (nn < count) {
            float val = ftnh(a2[rg]);
            dst[(size_t)nn * 128 + hcol] = f2bf(val);
            if (nn == outnode) out[hcol] = val;
          }
        }
        __syncthreads();
      }
    }
  }
}

extern "C" void kernel_launch(void* const* d_in, const int* in_sizes, int n_in,
                              void* d_out, int out_size, void* d_ws, size_t ws_size,
                              hipStream_t stream) {
  const int* labels = (const int*)d_in[0];
  const float* emb = (const float*)d_in[1];
  const float* w_ih_f = (const float*)d_in[2];
  const float* w_hh_f = (const float*)d_in[3];
  const float* b_ih_f = (const float*)d_in[4];
  const float* b_hh_f = (const float*)d_in[5];
  const float* w_ih_b = (const float*)d_in[6];
  const float* w_hh_b = (const float*)d_in[7];
  const float* b_ih_b = (const float*)d_in[8];
  const float* b_hh_b = (const float*)d_in[9];
  const float* lin_w = (const float*)d_in[10];
  const float* lin_b = (const float*)d_in[11];
  float* out = (float*)d_out;

  // enc only for nodes < offset(8)=21845 (levels 0..7); leaves are dedup'd.
  ushort* enc = (ushort*)d_ws;                    // 21845*128 bf16
  ushort* wrep = enc + 21845 * 128;               // 262144
  ushort* emb_bf = wrep + 262144;                 // 131072
  ushort* lwrep = emb_bf + 131072;                // 32768
  ushort* ltab = lwrep + 32768;                   // 1024*128 leaf table

  repack_all<<<1664, 256, 0, stream>>>(w_ih_f, w_hh_f, w_ih_b, w_hh_b, emb,
                                       lin_w, wrep, emb_bf, lwrep);

  // Leaf table: 1024 vocab entries, seq=[x,x] (T=2), x = emb_bf[v].
  tree_scan3<1><<<64, 512, 0, stream>>>(
      nullptr, emb_bf, wrep, b_ih_f, b_hh_f, b_ih_b, b_hh_b, lwrep, lin_b,
      nullptr, nullptr, 0, ltab, out, -1, 1024, 2, 64);

  for (int level = 7; level >= 0; --level) {
    const int start = ((1 << (2 * level)) - 1) / 3;
    const int count = 1 << (2 * level);
    const int cstart = start + count;  // offset(level+1)
    const int ngroups = (count + 15) >> 4;
    const int outnode = (level == 0) ? 0 : -1;
    if (level == 7) {
      // children are leaves: rows from leaf table via labels
      tree_scan3<4><<<256, 512, 0, stream>>>(
          labels + start, emb_bf, wrep, b_ih_f, b_hh_f, b_ih_b, b_hh_b, lwrep,
          lin_b, ltab, labels, cstart, enc + (size_t)start * 128, out, outnode,
          count, 6, ngroups);
    } else {
      tree_scan3<1><<<ngroups, 512, 0, stream>>>(
          labels + start, emb_bf, wrep, b_ih_f, b_hh_f, b_ih_b, b_hh_b, lwrep,
          lin_b, enc, nullptr, cstart, enc + (size_t)start * 128, out, outnode,
          count, 6, ngroups);
    }
  }
}

// Round 6
// 348.842 us; speedup vs baseline: 1.3703x; 1.0126x over previous
//
#include <hip/hip_runtime.h>
#include <hip/hip_bf16.h>

typedef __attribute__((ext_vector_type(8))) short bf16x8;
typedef __attribute__((ext_vector_type(4))) float f32x4;

__device__ __forceinline__ ushort f2bf(float f) {
  union { float f; unsigned u; } v; v.f = f;
  unsigned u = v.u;
  return (ushort)((u + 0x7FFFu + ((u >> 16) & 1u)) >> 16);
}
__device__ __forceinline__ float fsig(float x) {
  return __builtin_amdgcn_rcpf(1.0f + __expf(-x));
}
__device__ __forceinline__ float ftnh(float x) {
  float e = __expf(2.0f * x);
  return 1.0f - 2.0f * __builtin_amdgcn_rcpf(e + 1.0f);
}
__device__ __forceinline__ f32x4 MF(bf16x8 a, bf16x8 b, f32x4 c) {
  return __builtin_amdgcn_mfma_f32_16x16x32_bf16(a, b, c, 0, 0, 0);
}

// Repack layout (ushort units):
//  [0,131072)        whhrep [dir2][w8][lane64][frag16][8]
//  [131072,262144)   wihrep [dir2][wq4][j8][kk4][lane64][8]
//  [262144,294912)   linrep [w8][kk8][lane64][8]
//  [294912,425984)   emb_bf [1024][128]
__global__ __launch_bounds__(256) void repack_all2(
    const float* __restrict__ wihf, const float* __restrict__ whhf,
    const float* __restrict__ wihb, const float* __restrict__ whhb,
    const float* __restrict__ emb, const float* __restrict__ linw,
    ushort* __restrict__ wall) {
  int i = blockIdx.x * 256 + threadIdx.x;
  if (i < 131072) {
    int e = i & 7, f = (i >> 3) & 15, lane = (i >> 7) & 63, w = (i >> 13) & 7,
        d = (i >> 16) & 1;
    int nt = f >> 2, kk = f & 3;
    int pcol = w * 64 + nt * 16 + (lane & 15);
    int g = (pcol >> 4) & 3, h = (pcol >> 6) * 16 + (pcol & 15);
    int k = kk * 32 + (lane >> 4) * 8 + e;
    const float* src = d ? whhb : whhf;
    wall[i] = f2bf(src[(g * 128 + h) * 128 + k]);
  } else if (i < 262144) {
    int r = i - 131072;
    int e = r & 7, lane = (r >> 3) & 63, kk = (r >> 9) & 3, j = (r >> 11) & 7,
        wq = (r >> 14) & 3, d = (r >> 16) & 1;
    int pcol = wq * 128 + j * 16 + (lane & 15);
    int g = (pcol >> 4) & 3, h = (pcol >> 6) * 16 + (pcol & 15);
    int k = kk * 32 + (lane >> 4) * 8 + e;
    const float* src = d ? wihb : wihf;
    wall[i] = f2bf(src[(g * 128 + h) * 128 + k]);
  } else if (i < 294912) {
    int r = i - 262144;
    int e = r & 7, lane = (r >> 3) & 63, kk = (r >> 9) & 7, w = (r >> 12) & 7;
    int col = w * 16 + (lane & 15);
    int k = kk * 32 + (lane >> 4) * 8 + e;
    wall[i] = f2bf(linw[col * 256 + k]);
  } else if (i < 425984) {
    int r = i - 294912;
    wall[i] = f2bf(emb[r]);
  }
}

// Gates of the 1024 vocab embeddings: gxv[v][dir*512 + pcol] f32 (no bias).
__global__ __launch_bounds__(512) void gate_vocab(
    const ushort* __restrict__ emb_bf, const ushort* __restrict__ wihrep,
    float* __restrict__ gxv) {
  __shared__ __align__(16) ushort sT[2048];
  const int tid = threadIdx.x;
  const int w = tid >> 6, l = tid & 63, hlo = l & 15, lg = l >> 4;
  const int r0 = lg * 4;
  const int v0 = blockIdx.x * 16;
  {
    int row = tid >> 5, col0 = (tid & 31) * 4;
    *(ushort4*)(sT + row * 128 + (col0 ^ ((row & 7) << 3))) =
        *(const ushort4*)(emb_bf + (v0 + row) * 128 + col0);
  }
  __syncthreads();
  const int d = w >> 2, wq = w & 3;
  const ushort* wp = wihrep + (d * 4 + wq) * 16384 + l * 8;
  bf16x8 wf[32];
#pragma unroll
  for (int j = 0; j < 8; ++j)
#pragma unroll
    for (int kk = 0; kk < 4; ++kk)
      wf[j * 4 + kk] = *(const bf16x8*)(wp + j * 2048 + kk * 512);
  bf16x8 a[4];
#pragma unroll
  for (int kk = 0; kk < 4; ++kk)
    a[kk] = *(const bf16x8*)(sT + hlo * 128 + ((kk * 32 + lg * 8) ^ ((hlo & 7) << 3)));
  f32x4 acc[8];
#pragma unroll
  for (int j = 0; j < 8; ++j) { f32x4 z = {0.f, 0.f, 0.f, 0.f}; acc[j] = z; }
#pragma unroll
  for (int kk = 0; kk < 4; ++kk)
#pragma unroll
    for (int j = 0; j < 8; ++j) acc[j] = MF(a[kk], wf[j * 4 + kk], acc[j]);
#pragma unroll
  for (int j = 0; j < 8; ++j)
#pragma unroll
    for (int rg = 0; rg < 4; ++rg)
      gxv[(size_t)(v0 + r0 + rg) * 1024 + d * 512 + wq * 128 + j * 16 + hlo] =
          acc[j][rg];
}

// finish: head tanh([hf|hb]@linW^T+lb)  (+ optional out row 0)
//         then gates of the result -> gdst rows (tile0+r-gshift), f32.
__global__ __launch_bounds__(512) void finish_k(
    const ushort* __restrict__ hsrc, int hcap, int row0,
    const ushort* __restrict__ linrep, const float* __restrict__ linb,
    const ushort* __restrict__ wihrep, float* __restrict__ gdst, int gshift,
    float* __restrict__ outp) {
  __shared__ __align__(16) ushort sT[2048];
  const int tid = threadIdx.x;
  const int w = tid >> 6, l = tid & 63, hlo = l & 15, lg = l >> 4;
  const int r0 = lg * 4;
  const int tile0 = row0 + blockIdx.x * 16;

  // head
  const ushort* lp = linrep + w * 4096 + l * 8;
  const float lb = linb[w * 16 + hlo];
  f32x4 hac = {lb, lb, lb, lb};
#pragma unroll
  for (int kk = 0; kk < 8; ++kk) {
    bf16x8 lf = *(const bf16x8*)(lp + kk * 512);
    const ushort* hp = hsrc + (kk < 4 ? 0 : (size_t)hcap * 128) +
                       (size_t)(tile0 + hlo) * 128 + (kk & 3) * 32 + lg * 8;
    bf16x8 af = *(const bf16x8*)hp;
    hac = MF(af, lf, hac);
  }
  float v[4];
#pragma unroll
  for (int rg = 0; rg < 4; ++rg) v[rg] = ftnh(hac[rg]);
  if (outp && tile0 == 0 && lg == 0) outp[w * 16 + hlo] = v[0];
#pragma unroll
  for (int rg = 0; rg < 4; ++rg) {
    int rr = r0 + rg;
    sT[rr * 128 + ((w * 16 + hlo) ^ ((rr & 7) << 3))] = f2bf(v[rg]);
  }
  __syncthreads();

  if (gdst) {
    const int d = w >> 2, wq = w & 3;
    const ushort* wp = wihrep + (d * 4 + wq) * 16384 + l * 8;
    bf16x8 wf[32];
#pragma unroll
    for (int j = 0; j < 8; ++j)
#pragma unroll
      for (int kk = 0; kk < 4; ++kk)
        wf[j * 4 + kk] = *(const bf16x8*)(wp + j * 2048 + kk * 512);
    bf16x8 a[4];
#pragma unroll
    for (int kk = 0; kk < 4; ++kk)
      a[kk] =
          *(const bf16x8*)(sT + hlo * 128 + ((kk * 32 + lg * 8) ^ ((hlo & 7) << 3)));
    f32x4 acc[8];
#pragma unroll
    for (int j = 0; j < 8; ++j) { f32x4 z = {0.f, 0.f, 0.f, 0.f}; acc[j] = z; }
#pragma unroll
    for (int kk = 0; kk < 4; ++kk)
#pragma unroll
      for (int j = 0; j < 8; ++j) acc[j] = MF(a[kk], wf[j * 4 + kk], acc[j]);
#pragma unroll
    for (int j = 0; j < 8; ++j)
#pragma unroll
      for (int rg = 0; rg < 4; ++rg)
        gdst[(size_t)(tile0 + r0 + rg - gshift) * 1024 + d * 512 + wq * 128 +
             j * 16 + hlo] = acc[j][rg];
  }
}

// h-recurrence scan. grid (ngroups, 2): blockIdx.y = dir. Only Whh in regs.
// Gates read from gx (x steps, row = xlab?xlab[n]:n) and gcs (child steps,
// row = CLAB ? clab[cbase+n*4+ci] : n*4+ci-gcbase), both f32 stride 1024.
template <int T, bool CLAB>
__global__ __launch_bounds__(512, 4) void scan_k(
    const ushort* __restrict__ whhrep, const float* __restrict__ bihf,
    const float* __restrict__ bhhf, const float* __restrict__ bihb,
    const float* __restrict__ bhhb, const float* __restrict__ gx,
    const int* __restrict__ xlab, const float* __restrict__ gcs,
    const int* __restrict__ clab, int cbase, int gcbase,
    ushort* __restrict__ hdst, int hcap, int goff, int count) {
  __shared__ __align__(16) ushort sH[2][2048];
  const int tid = threadIdx.x;
  const int w = tid >> 6, l = tid & 63, hlo = l & 15, lg = l >> 4;
  const int r0 = lg * 4;
  const int hcol = w * 16 + hlo;
  const int k0 = lg * 8;
  const int axswz = (hlo & 7) << 3;
  const int dir = blockIdx.y;
  const int node0 = (goff + blockIdx.x) * 16;
  const int gcol = dir * 512 + w * 64 + hlo;

  // Whh B-fragments
  bf16x8 whh[16];
  {
    const ushort* p = whhrep + dir * 65536 + w * 8192 + l * 128;
#pragma unroll
    for (int f = 0; f < 16; ++f) whh[f] = *(const bf16x8*)(p + f * 8);
  }
  const float* bih = dir ? bihb : bihf;
  const float* bhh = dir ? bhhb : bhhf;
  float bs[4];
#pragma unroll
  for (int nt = 0; nt < 4; ++nt) bs[nt] = bih[nt * 128 + hcol] + bhh[nt * 128 + hcol];

  int nb[4], xrow[4];
#pragma unroll
  for (int rg = 0; rg < 4; ++rg) {
    nb[rg] = node0 + r0 + rg;
    xrow[rg] = xlab ? xlab[nb[rg]] : nb[rg];
  }
  int lnext[4];
  float c_st[4], hn[4];

#pragma unroll
  for (int t = 0; t < T; ++t) {
    const bool isx = (t == 0) || (t == T - 1);
    f32x4 a4[4];
#pragma unroll
    for (int rg = 0; rg < 4; ++rg) {
      int grow;
      if (isx)
        grow = xrow[rg];
      else if (CLAB)
        grow = lnext[rg];
      else
        grow = nb[rg] * 4 + (dir ? (T - 2 - t) : (t - 1)) - gcbase;
      const float* gp = (isx ? gx : gcs) + (size_t)grow * 1024 + gcol;
#pragma unroll
      for (int nt = 0; nt < 4; ++nt) a4[nt][rg] = gp[nt * 16];
    }
    if (CLAB && T > 2 && t <= T - 3) {  // labels for step t+1's child
      const int cin = dir ? (T - 3 - t) : t;
#pragma unroll
      for (int rg = 0; rg < 4; ++rg) lnext[rg] = clab[cbase + nb[rg] * 4 + cin];
    }
#pragma unroll
    for (int nt = 0; nt < 4; ++nt)
#pragma unroll
      for (int rg = 0; rg < 4; ++rg) a4[nt][rg] += bs[nt];

    if (t > 0) {
      bf16x8 ah[4];
#pragma unroll
      for (int kk = 0; kk < 4; ++kk)
        ah[kk] = *(const bf16x8*)(sH[(t + 1) & 1] + hlo * 128 +
                                  ((kk * 32 + k0) ^ axswz));
#pragma unroll
      for (int kk = 0; kk < 4; ++kk)
#pragma unroll
        for (int nt = 0; nt < 4; ++nt) a4[nt] = MF(ah[kk], whh[nt * 4 + kk], a4[nt]);
    }

#pragma unroll
    for (int rg = 0; rg < 4; ++rg) {
      float iv = fsig(a4[0][rg]);
      float fv = fsig(a4[1][rg]);
      float gv = ftnh(a4[2][rg]);
      float ov = fsig(a4[3][rg]);
      float c = (t == 0) ? (iv * gv) : (fv * c_st[rg] + iv * gv);
      c_st[rg] = c;
      hn[rg] = ov * ftnh(c);
    }

    if (t < T - 1) {
#pragma unroll
      for (int rg = 0; rg < 4; ++rg) {
        int rr = r0 + rg;
        sH[t & 1][rr * 128 + (hcol ^ ((rr & 7) << 3))] = f2bf(hn[rg]);
      }
      __syncthreads();
    } else {
#pragma unroll
      for (int rg = 0; rg < 4; ++rg) {
        if (nb[rg] < count)
          hdst[(size_t)dir * hcap * 128 + (size_t)nb[rg] * 128 + hcol] = f2bf(hn[rg]);
      }
    }
  }
}

extern "C" void kernel_launch(void* const* d_in, const int* in_sizes, int n_in,
                              void* d_out, int out_size, void* d_ws, size_t ws_size,
                              hipStream_t stream) {
  const int* labels = (const int*)d_in[0];
  const float* emb = (const float*)d_in[1];
  const float* w_ih_f = (const float*)d_in[2];
  const float* w_hh_f = (const float*)d_in[3];
  const float* b_ih_f = (const float*)d_in[4];
  const float* b_hh_f = (const float*)d_in[5];
  const float* w_ih_b = (const float*)d_in[6];
  const float* w_hh_b = (const float*)d_in[7];
  const float* b_ih_b = (const float*)d_in[8];
  const float* b_hh_b = (const float*)d_in[9];
  const float* lin_w = (const float*)d_in[10];
  const float* lin_b = (const float*)d_in[11];
  float* out = (float*)d_out;

  float* gc = (float*)d_ws;                 // 4096*1024 f32
  float* gxv = gc + 4096 * 1024;            // 1024*1024 f32
  float* gcv = gxv + 1024 * 1024;           // 1024*1024 f32
  ushort* hA = (ushort*)(gcv + 1024 * 1024);  // [2][16384][128] bf16
  ushort* hB = hA + 2 * 16384 * 128;          // [2][4096][128] bf16
  ushort* wall = hB + 2 * 4096 * 128;         // repack area
  ushort* whhrep = wall;
  ushort* wihrep = wall + 131072;
  ushort* linrep = wall + 262144;
  ushort* emb_bf = wall + 294912;

  repack_all2<<<1664, 256, 0, stream>>>(w_ih_f, w_hh_f, w_ih_b, w_hh_b, emb,
                                        lin_w, wall);
  gate_vocab<<<64, 512, 0, stream>>>(emb_bf, wihrep, gxv);

  // leaf scan over vocab (T=2) -> hB ; leaf finish -> gcv
  scan_k<2, false><<<dim3(64, 2), 512, 0, stream>>>(
      whhrep, b_ih_f, b_hh_f, b_ih_b, b_hh_b, gxv, nullptr, gxv, nullptr, 0, 0,
      hB, 4096, 0, 1024);
  finish_k<<<64, 512, 0, stream>>>(hB, 4096, 0, linrep, lin_b, wihrep, gcv, 0,
                                   nullptr);

  // L7: 16384 nodes; x labels at 5461, child (leaf) labels at 21845 -> gcv
  scan_k<6, true><<<dim3(1024, 2), 512, 0, stream>>>(
      whhrep, b_ih_f, b_hh_f, b_ih_b, b_hh_b, gxv, labels + 5461, gcv, labels,
      21845, 0, hA, 16384, 0, 16384);

  // L7 finish / L6 scan in 4 chunks of 4096 child rows (1024 L6 nodes)
  for (int c = 0; c < 4; ++c) {
    finish_k<<<256, 512, 0, stream>>>(hA, 16384, c * 4096, linrep, lin_b,
                                      wihrep, gc, c * 4096, nullptr);
    scan_k<6, false><<<dim3(64, 2), 512, 0, stream>>>(
        whhrep, b_ih_f, b_hh_f, b_ih_b, b_hh_b, gxv, labels + 1365, gc, nullptr,
        0, c * 4096, hB, 4096, c * 64, 4096);
  }

  // remaining levels: finish(child level) -> gc ; scan(level)
  // level params: {start, count, hsrc/hdst alternate}
  // L6 finish (hB,4096 rows) -> gc ; L5 scan -> hA
  finish_k<<<256, 512, 0, stream>>>(hB, 4096, 0, linrep, lin_b, wihrep, gc, 0,
                                    nullptr);
  scan_k<6, false><<<dim3(64, 2), 512, 0, stream>>>(
      whhrep, b_ih_f, b_hh_f, b_ih_b, b_hh_b, gxv, labels + 341, gc, nullptr, 0,
      0, hA, 16384, 0, 1024);
  // L5 finish (1024 rows) -> gc ; L4 scan (256 nodes) -> hB
  finish_k<<<64, 512, 0, stream>>>(hA, 16384, 0, linrep, lin_b, wihrep, gc, 0,
                                   nullptr);
  scan_k<6, false><<<dim3(16, 2), 512, 0, stream>>>(
      whhrep, b_ih_f, b_hh_f, b_ih_b, b_hh_b, gxv, labels + 85, gc, nullptr, 0,
      0, hB, 4096, 0, 256);
  // L4 finish (256 rows) -> gc ; L3 scan (64) -> hA
  finish_k<<<16, 512, 0, stream>>>(hB, 4096, 0, linrep, lin_b, wihrep, gc, 0,
                                   nullptr);
  scan_k<6, false><<<dim3(4, 2), 512, 0, stream>>>(
      whhrep, b_ih_f, b_hh_f, b_ih_b, b_hh_b, gxv, labels + 21, gc, nullptr, 0,
      0, hA, 16384, 0, 64);
  // L3 finish (64 rows) -> gc ; L2 scan (16) -> hB
  finish_k<<<4, 512, 0, stream>>>(hA, 16384, 0, linrep, lin_b, wihrep, gc, 0,
                                  nullptr);
  scan_k<6, false><<<dim3(1, 2), 512, 0, stream>>>(
      whhrep, b_ih_f, b_hh_f, b_ih_b, b_hh_b, gxv, labels + 5, gc, nullptr, 0,
      0, hB, 4096, 0, 16);
  // L2 finish (16 rows) -> gc ; L1 scan (4) -> hA
  finish_k<<<1, 512, 0, stream>>>(hB, 4096, 0, linrep, lin_b, wihrep, gc, 0,
                                  nullptr);
  scan_k<6, false><<<dim3(1, 2), 512, 0, stream>>>(
      whhrep, b_ih_f, b_hh_f, b_ih_b, b_hh_b, gxv, labels + 1, gc, nullptr, 0,
      0, hA, 16384, 0, 4);
  // L1 finish (4 rows) -> gc ; L0 scan (1) -> hB
  finish_k<<<1, 512, 0, stream>>>(hA, 16384, 0, linrep, lin_b, wihrep, gc, 0,
                                  nullptr);
  scan_k<6, false><<<dim3(1, 2), 512, 0, stream>>>(
      whhrep, b_ih_f, b_hh_f, b_ih_b, b_hh_b, gxv, labels + 0, gc, nullptr, 0,
      0, hB, 4096, 0, 1);
  // L0 finish: head only, write out
  finish_k<<<1, 512, 0, stream>>>(hB, 4096, 0, linrep, lin_b, wihrep, nullptr,
                                  0, out);
}

// Round 7
// 294.724 us; speedup vs baseline: 1.6219x; 1.1836x over previous
//
#include <hip/hip_runtime.h>
#include <hip/hip_bf16.h>

typedef __attribute__((ext_vector_type(8))) short bf16x8;
typedef __attribute__((ext_vector_type(4))) float f32x4;

__device__ __forceinline__ ushort f2bf(float f) {
  union { float f; unsigned u; } v; v.f = f;
  unsigned u = v.u;
  return (ushort)((u + 0x7FFFu + ((u >> 16) & 1u)) >> 16);
}
__device__ __forceinline__ float bf2f(ushort u) {
  union { unsigned u; float f; } v; v.u = ((unsigned)u) << 16;
  return v.f;
}
__device__ __forceinline__ float fsig(float x) {
  return __builtin_amdgcn_rcpf(1.0f + __expf(-x));
}
__device__ __forceinline__ float ftnh(float x) {
  float e = __expf(2.0f * x);
  return 1.0f - 2.0f * __builtin_amdgcn_rcpf(e + 1.0f);
}
__device__ __forceinline__ f32x4 MF(bf16x8 a, bf16x8 b, f32x4 c) {
  return __builtin_amdgcn_mfma_f32_16x16x32_bf16(a, b, c, 0, 0, 0);
}

// Repack layout (ushort units) in `wall`:
//  [0,131072)        whhrep [dir2][w8][lane64][frag16][8]
//  [131072,262144)   wihrep [dir2][wq4][j8][kk4][lane64][8]
//  [262144,294912)   linrep [w8][kk8][lane64][8]
//  [294912,425984)   emb_bf [1024][128]
__global__ __launch_bounds__(256) void repack_all2(
    const float* __restrict__ wihf, const float* __restrict__ whhf,
    const float* __restrict__ wihb, const float* __restrict__ whhb,
    const float* __restrict__ emb, const float* __restrict__ linw,
    ushort* __restrict__ wall) {
  int i = blockIdx.x * 256 + threadIdx.x;
  if (i < 131072) {
    int e = i & 7, f = (i >> 3) & 15, lane = (i >> 7) & 63, w = (i >> 13) & 7,
        d = (i >> 16) & 1;
    int nt = f >> 2, kk = f & 3;
    int pcol = w * 64 + nt * 16 + (lane & 15);
    int g = (pcol >> 4) & 3, h = (pcol >> 6) * 16 + (pcol & 15);
    int k = kk * 32 + (lane >> 4) * 8 + e;
    const float* src = d ? whhb : whhf;
    wall[i] = f2bf(src[(g * 128 + h) * 128 + k]);
  } else if (i < 262144) {
    int r = i - 131072;
    int e = r & 7, lane = (r >> 3) & 63, kk = (r >> 9) & 3, j = (r >> 11) & 7,
        wq = (r >> 14) & 3, d = (r >> 16) & 1;
    int pcol = wq * 128 + j * 16 + (lane & 15);
    int g = (pcol >> 4) & 3, h = (pcol >> 6) * 16 + (pcol & 15);
    int k = kk * 32 + (lane >> 4) * 8 + e;
    const float* src = d ? wihb : wihf;
    wall[i] = f2bf(src[(g * 128 + h) * 128 + k]);
  } else if (i < 294912) {
    int r = i - 262144;
    int e = r & 7, lane = (r >> 3) & 63, kk = (r >> 9) & 7, w = (r >> 12) & 7;
    int col = w * 16 + (lane & 15);
    int k = kk * 32 + (lane >> 4) * 8 + e;
    wall[i] = f2bf(linw[col * 256 + k]);
  } else if (i < 425984) {
    int r = i - 294912;
    wall[i] = f2bf(emb[r]);
  }
}

// x-gates of the 1024 vocab embeddings -> gxv[v][dir][hid][gate] bf16 (no bias)
__global__ __launch_bounds__(512) void gate_vocab(
    const ushort* __restrict__ emb_bf, const ushort* __restrict__ wihrep,
    ushort* __restrict__ gxv) {
  __shared__ __align__(16) ushort sT[2048];
  const int tid = threadIdx.x;
  const int w = tid >> 6, l = tid & 63, hlo = l & 15, lg = l >> 4;
  const int r0 = lg * 4, k0 = lg * 8;
  const int v0 = blockIdx.x * 16;
  {
    int row = tid >> 5, col0 = (tid & 31) * 4;
    *(ushort4*)(sT + row * 128 + (col0 ^ ((row & 7) << 3))) =
        *(const ushort4*)(emb_bf + (size_t)(v0 + row) * 128 + col0);
  }
  __syncthreads();
  const int d = w >> 2, wq = w & 3;
  const ushort* wp = wihrep + (size_t)(d * 4 + wq) * 16384 + l * 8;
  bf16x8 wf[32];
#pragma unroll
  for (int j = 0; j < 8; ++j)
#pragma unroll
    for (int kk = 0; kk < 4; ++kk)
      wf[j * 4 + kk] = *(const bf16x8*)(wp + j * 2048 + kk * 512);
  bf16x8 a[4];
#pragma unroll
  for (int kk = 0; kk < 4; ++kk)
    a[kk] = *(const bf16x8*)(sT + hlo * 128 + ((kk * 32 + k0) ^ ((hlo & 7) << 3)));
  f32x4 acc[8];
#pragma unroll
  for (int j = 0; j < 8; ++j) { f32x4 z = {0.f, 0.f, 0.f, 0.f}; acc[j] = z; }
#pragma unroll
  for (int kk = 0; kk < 4; ++kk)
#pragma unroll
    for (int j = 0; j < 8; ++j) acc[j] = MF(a[kk], wf[j * 4 + kk], acc[j]);
#pragma unroll
  for (int p = 0; p < 2; ++p)
#pragma unroll
    for (int rg = 0; rg < 4; ++rg) {
      int row = v0 + r0 + rg;
      int hid = (wq * 2 + p) * 16 + hlo;
      ushort4 q = {f2bf(acc[p * 4 + 0][rg]), f2bf(acc[p * 4 + 1][rg]),
                   f2bf(acc[p * 4 + 2][rg]), f2bf(acc[p * 4 + 3][rg])};
      *(ushort4*)(gxv + (size_t)row * 1024 + d * 512 + hid * 4) = q;
    }
}

// leaf scan over vocab: T=2, seq=[x,x] -> hL[2][1024][128]
__global__ __launch_bounds__(512) void leaf_scan(
    const ushort* __restrict__ gxv, const ushort* __restrict__ whhrep,
    const float* __restrict__ bihf, const float* __restrict__ bhhf,
    const float* __restrict__ bihb, const float* __restrict__ bhhb,
    ushort* __restrict__ hL) {
  __shared__ __align__(16) ushort sH[2048];
  const int tid = threadIdx.x;
  const int w = tid >> 6, l = tid & 63, hlo = l & 15, lg = l >> 4;
  const int r0 = lg * 4, k0 = lg * 8;
  const int hcol = w * 16 + hlo;
  const int d = blockIdx.y;
  const int v0 = blockIdx.x * 16;

  bf16x8 whh[16];
  {
    const ushort* p = whhrep + d * 65536 + w * 8192 + l * 128;
#pragma unroll
    for (int f = 0; f < 16; ++f) whh[f] = *(const bf16x8*)(p + f * 8);
  }
  const float* bih = d ? bihb : bihf;
  const float* bhh = d ? bhhb : bhhf;
  float bs[4];
#pragma unroll
  for (int nt = 0; nt < 4; ++nt) bs[nt] = bih[nt * 128 + hcol] + bhh[nt * 128 + hcol];

  ushort4 xg[4];
#pragma unroll
  for (int rg = 0; rg < 4; ++rg)
    xg[rg] = *(const ushort4*)(gxv + (size_t)(v0 + r0 + rg) * 1024 + d * 512 + hcol * 4);

  float c_st[4], hn[4];
  // t = 0 (h = 0)
#pragma unroll
  for (int rg = 0; rg < 4; ++rg) {
    float g0 = bf2f(((const ushort*)&xg[rg])[0]) + bs[0];
    float g1 = bf2f(((const ushort*)&xg[rg])[1]) + bs[1];
    float g2 = bf2f(((const ushort*)&xg[rg])[2]) + bs[2];
    float g3 = bf2f(((const ushort*)&xg[rg])[3]) + bs[3];
    float c = fsig(g0) * ftnh(g2);
    c_st[rg] = c;
    hn[rg] = fsig(g3) * ftnh(c);
  }
#pragma unroll
  for (int rg = 0; rg < 4; ++rg) {
    int rr = r0 + rg;
    sH[rr * 128 + (hcol ^ ((rr & 7) << 3))] = f2bf(hn[rg]);
  }
  __syncthreads();
  // t = 1
  f32x4 a4[4];
#pragma unroll
  for (int rg = 0; rg < 4; ++rg)
#pragma unroll
    for (int nt = 0; nt < 4; ++nt)
      a4[nt][rg] = bf2f(((const ushort*)&xg[rg])[nt]) + bs[nt];
  bf16x8 ah[4];
#pragma unroll
  for (int kk = 0; kk < 4; ++kk)
    ah[kk] = *(const bf16x8*)(sH + hlo * 128 + ((kk * 32 + k0) ^ ((hlo & 7) << 3)));
#pragma unroll
  for (int kk = 0; kk < 4; ++kk)
#pragma unroll
    for (int nt = 0; nt < 4; ++nt) a4[nt] = MF(ah[kk], whh[nt * 4 + kk], a4[nt]);
#pragma unroll
  for (int rg = 0; rg < 4; ++rg) {
    float iv = fsig(a4[0][rg]);
    float fv = fsig(a4[1][rg]);
    float gv = ftnh(a4[2][rg]);
    float ov = fsig(a4[3][rg]);
    float c = fv * c_st[rg] + iv * gv;
    hn[rg] = ov * ftnh(c);
    hL[((size_t)d * 1024 + (v0 + r0 + rg)) * 128 + hcol] = f2bf(hn[rg]);
  }
}

// leaf finish: enc = tanh(head), gates(enc) -> gcv[1024][dir][hid][gate]
__global__ __launch_bounds__(512) void leaf_fin(
    const ushort* __restrict__ hL, const ushort* __restrict__ linrep,
    const float* __restrict__ linb, const ushort* __restrict__ wihrep,
    ushort* __restrict__ gcv) {
  __shared__ __align__(16) ushort sT[2048];
  const int tid = threadIdx.x;
  const int w = tid >> 6, l = tid & 63, hlo = l & 15, lg = l >> 4;
  const int r0 = lg * 4, k0 = lg * 8;
  const int v0 = blockIdx.x * 16;
  const float lb = linb[w * 16 + hlo];
  f32x4 hac = {lb, lb, lb, lb};
#pragma unroll
  for (int kk = 0; kk < 8; ++kk) {
    bf16x8 lf = *(const bf16x8*)(linrep + w * 4096 + kk * 512 + l * 8);
    bf16x8 af = *(const bf16x8*)(hL + ((size_t)(kk >> 2) * 1024 + v0 + hlo) * 128 +
                                 (kk & 3) * 32 + k0);
    hac = MF(af, lf, hac);
  }
#pragma unroll
  for (int rg = 0; rg < 4; ++rg) {
    int rr = r0 + rg;
    sT[rr * 128 + ((w * 16 + hlo) ^ ((rr & 7) << 3))] = f2bf(ftnh(hac[rg]));
  }
  __syncthreads();
  const int d = w >> 2, wq = w & 3;
  const ushort* wp = wihrep + (size_t)(d * 4 + wq) * 16384 + l * 8;
  bf16x8 wf[32];
#pragma unroll
  for (int j = 0; j < 8; ++j)
#pragma unroll
    for (int kk = 0; kk < 4; ++kk)
      wf[j * 4 + kk] = *(const bf16x8*)(wp + j * 2048 + kk * 512);
  bf16x8 a[4];
#pragma unroll
  for (int kk = 0; kk < 4; ++kk)
    a[kk] = *(const bf16x8*)(sT + hlo * 128 + ((kk * 32 + k0) ^ ((hlo & 7) << 3)));
  f32x4 acc[8];
#pragma unroll
  for (int j = 0; j < 8; ++j) { f32x4 z = {0.f, 0.f, 0.f, 0.f}; acc[j] = z; }
#pragma unroll
  for (int kk = 0; kk < 4; ++kk)
#pragma unroll
    for (int j = 0; j < 8; ++j) acc[j] = MF(a[kk], wf[j * 4 + kk], acc[j]);
#pragma unroll
  for (int p = 0; p < 2; ++p)
#pragma unroll
    for (int rg = 0; rg < 4; ++rg) {
      int row = v0 + r0 + rg;
      int hid = (wq * 2 + p) * 16 + hlo;
      ushort4 q = {f2bf(acc[p * 4 + 0][rg]), f2bf(acc[p * 4 + 1][rg]),
                   f2bf(acc[p * 4 + 2][rg]), f2bf(acc[p * 4 + 3][rg])};
      *(ushort4*)(gcv + (size_t)row * 1024 + d * 512 + hid * 4) = q;
    }
}

// L7 scan: x-gates + child-gates gathered from vocab tables -> h7
__global__ __launch_bounds__(512) void scan7_k(
    const int* __restrict__ labels, const ushort* __restrict__ gxv,
    const ushort* __restrict__ gcv, const ushort* __restrict__ whhrep,
    const float* __restrict__ bihf, const float* __restrict__ bhhf,
    const float* __restrict__ bihb, const float* __restrict__ bhhb,
    ushort* __restrict__ h7) {
  __shared__ __align__(16) ushort sH[2][2048];
  const int tid = threadIdx.x;
  const int w = tid >> 6, l = tid & 63, hlo = l & 15, lg = l >> 4;
  const int r0 = lg * 4, k0 = lg * 8;
  const int hcol = w * 16 + hlo;
  const int d = blockIdx.y;
  const int g = blockIdx.x;

  bf16x8 whh[16];
  {
    const ushort* p = whhrep + d * 65536 + w * 8192 + l * 128;
#pragma unroll
    for (int f = 0; f < 16; ++f) whh[f] = *(const bf16x8*)(p + f * 8);
  }
  const float* bih = d ? bihb : bihf;
  const float* bhh = d ? bhhb : bhhf;
  float bs[4];
#pragma unroll
  for (int nt = 0; nt < 4; ++nt) bs[nt] = bih[nt * 128 + hcol] + bhh[nt * 128 + hcol];

  int nn[4];
  ushort4 xg[4];
#pragma unroll
  for (int rg = 0; rg < 4; ++rg) {
    nn[rg] = g * 16 + r0 + rg;
    int xr = labels[5461 + nn[rg]];
    xg[rg] = *(const ushort4*)(gxv + (size_t)xr * 1024 + d * 512 + hcol * 4);
  }
  ushort4 cg[2][4];
  {
    const int ci = d ? 3 : 0;
#pragma unroll
    for (int rg = 0; rg < 4; ++rg) {
      int cl = labels[21845 + nn[rg] * 4 + ci];
      cg[1][rg] = *(const ushort4*)(gcv + (size_t)cl * 1024 + d * 512 + hcol * 4);
    }
  }
  float c_st[4], hn[4];
#pragma unroll
  for (int t = 0; t < 6; ++t) {
    const bool isx = (t == 0) || (t == 5);
    f32x4 a4[4];
#pragma unroll
    for (int rg = 0; rg < 4; ++rg) {
      ushort4 u = isx ? xg[rg] : cg[t & 1][rg];
#pragma unroll
      for (int nt = 0; nt < 4; ++nt)
        a4[nt][rg] = bf2f(((const ushort*)&u)[nt]) + bs[nt];
    }
    if (t >= 1 && t <= 3) {  // prefetch gates for step t+1
      const int ci = d ? (3 - t) : t;
#pragma unroll
      for (int rg = 0; rg < 4; ++rg) {
        int cl = labels[21845 + nn[rg] * 4 + ci];
        cg[(t + 1) & 1][rg] =
            *(const ushort4*)(gcv + (size_t)cl * 1024 + d * 512 + hcol * 4);
      }
    }
    if (t > 0) {
      bf16x8 ah[4];
#pragma unroll
      for (int kk = 0; kk < 4; ++kk)
        ah[kk] = *(const bf16x8*)(&sH[(t + 1) & 1][0] + hlo * 128 +
                                  ((kk * 32 + k0) ^ ((hlo & 7) << 3)));
#pragma unroll
      for (int kk = 0; kk < 4; ++kk)
#pragma unroll
        for (int nt = 0; nt < 4; ++nt) a4[nt] = MF(ah[kk], whh[nt * 4 + kk], a4[nt]);
    }
#pragma unroll
    for (int rg = 0; rg < 4; ++rg) {
      float iv = fsig(a4[0][rg]);
      float fv = fsig(a4[1][rg]);
      float gv = ftnh(a4[2][rg]);
      float ov = fsig(a4[3][rg]);
      float c = (t == 0) ? (iv * gv) : (fv * c_st[rg] + iv * gv);
      c_st[rg] = c;
      hn[rg] = ov * ftnh(c);
    }
    if (t < 5) {
#pragma unroll
      for (int rg = 0; rg < 4; ++rg) {
        int rr = r0 + rg;
        sH[t & 1][rr * 128 + (hcol ^ ((rr & 7) << 3))] = f2bf(hn[rg]);
      }
      __syncthreads();
    } else {
#pragma unroll
      for (int rg = 0; rg < 4; ++rg)
        h7[((size_t)d * 16384 + nn[rg]) * 128 + hcol] = f2bf(hn[rg]);
    }
  }
}

// Generic "embedded finish + scan" for levels 6..0.
__device__ __forceinline__ void scan_embed(
    int g, int d, int cnt, const int* __restrict__ xlab,
    const ushort* __restrict__ gxv, const ushort* __restrict__ hsrc,
    const ushort* __restrict__ wihrep, const ushort* __restrict__ whhrep,
    const ushort* __restrict__ linrep, const float* __restrict__ linb,
    const float* __restrict__ bihf, const float* __restrict__ bhhf,
    const float* __restrict__ bihb, const float* __restrict__ bhhb,
    ushort* __restrict__ hdst, ushort* sG, ushort* sHb, ushort* sT) {
  const int tid = threadIdx.x;
  const int w = tid >> 6, l = tid & 63, hlo = l & 15, lg = l >> 4;
  const int r0 = lg * 4, k0 = lg * 8;
  const int hcol = w * 16 + hlo;
  const int ccnt = 4 * cnt;

  // ---- embedded finish of child level: head + gates(dir d) -> sG ----
  bf16x8 wf[16];
  {
    const ushort* wp = wihrep + (size_t)(d * 4 + (w >> 1)) * 16384 +
                       (size_t)((w & 1) * 4) * 2048 + l * 8;
#pragma unroll
    for (int jj = 0; jj < 4; ++jj)
#pragma unroll
      for (int kk = 0; kk < 4; ++kk)
        wf[jj * 4 + kk] = *(const bf16x8*)(wp + jj * 2048 + kk * 512);
  }
  const float lb = linb[hcol];
  const int ntile = min(4, (ccnt - g * 64 + 15) >> 4);
  for (int tt = 0; tt < ntile; ++tt) {
    f32x4 hac = {lb, lb, lb, lb};
    int cr = g * 64 + tt * 16 + hlo;
    if (cr >= ccnt) cr = ccnt - 1;
#pragma unroll
    for (int kk = 0; kk < 8; ++kk) {
      bf16x8 lf = *(const bf16x8*)(linrep + w * 4096 + kk * 512 + l * 8);
      bf16x8 af = *(const bf16x8*)(hsrc + ((size_t)(kk >> 2) * ccnt + cr) * 128 +
                                   (kk & 3) * 32 + k0);
      hac = MF(af, lf, hac);
    }
    __syncthreads();
#pragma unroll
    for (int rg = 0; rg < 4; ++rg) {
      int rr = r0 + rg;
      sT[rr * 128 + (hcol ^ ((rr & 7) << 3))] = f2bf(ftnh(hac[rg]));
    }
    __syncthreads();
    bf16x8 a[4];
#pragma unroll
    for (int kk = 0; kk < 4; ++kk)
      a[kk] = *(const bf16x8*)(sT + hlo * 128 + ((kk * 32 + k0) ^ ((hlo & 7) << 3)));
    f32x4 acc[4];
#pragma unroll
    for (int jj = 0; jj < 4; ++jj) { f32x4 z = {0.f, 0.f, 0.f, 0.f}; acc[jj] = z; }
#pragma unroll
    for (int kk = 0; kk < 4; ++kk)
#pragma unroll
      for (int jj = 0; jj < 4; ++jj) acc[jj] = MF(a[kk], wf[jj * 4 + kk], acc[jj]);
    const int hid = (w >> 1) * 32 + (w & 1) * 16 + hlo;
#pragma unroll
    for (int rg = 0; rg < 4; ++rg) {
      int lrow = tt * 16 + r0 + rg;
      int sw = ((((lrow >> 4) & 3) ^ ((lrow >> 2) & 3)) << 4);
      ushort4 q = {f2bf(acc[0][rg]), f2bf(acc[1][rg]), f2bf(acc[2][rg]),
                   f2bf(acc[3][rg])};
      *(ushort4*)(sG + lrow * 512 + ((hid * 4) ^ sw)) = q;
    }
  }
  __syncthreads();

  // ---- scan ----
  bf16x8 whh[16];
  {
    const ushort* p = whhrep + d * 65536 + w * 8192 + l * 128;
#pragma unroll
    for (int f = 0; f < 16; ++f) whh[f] = *(const bf16x8*)(p + f * 8);
  }
  const float* bih = d ? bihb : bihf;
  const float* bhh = d ? bhhb : bhhf;
  float bs[4];
#pragma unroll
  for (int nt = 0; nt < 4; ++nt) bs[nt] = bih[nt * 128 + hcol] + bhh[nt * 128 + hcol];

  int nn[4];
  ushort4 xg[4];
#pragma unroll
  for (int rg = 0; rg < 4; ++rg) {
    nn[rg] = g * 16 + r0 + rg;
    int cl = nn[rg] < cnt ? nn[rg] : cnt - 1;
    int xr = xlab[cl];
    xg[rg] = *(const ushort4*)(gxv + (size_t)xr * 1024 + d * 512 + hcol * 4);
  }
  float c_st[4], hn[4];
#pragma unroll
  for (int t = 0; t < 6; ++t) {
    const bool isx = (t == 0) || (t == 5);
    f32x4 a4[4];
#pragma unroll
    for (int rg = 0; rg < 4; ++rg) {
      ushort4 u;
      if (isx) {
        u = xg[rg];
      } else {
        const int ci = d ? (4 - t) : (t - 1);
        int lrow = (r0 + rg) * 4 + ci;
        int sw = ((((lrow >> 4) & 3) ^ ((lrow >> 2) & 3)) << 4);
        u = *(const ushort4*)(sG + lrow * 512 + ((hcol * 4) ^ sw));
      }
#pragma unroll
      for (int nt = 0; nt < 4; ++nt)
        a4[nt][rg] = bf2f(((const ushort*)&u)[nt]) + bs[nt];
    }
    if (t > 0) {
      bf16x8 ah[4];
#pragma unroll
      for (int kk = 0; kk < 4; ++kk)
        ah[kk] = *(const bf16x8*)(sHb + ((t + 1) & 1) * 2048 + hlo * 128 +
                                  ((kk * 32 + k0) ^ ((hlo & 7) << 3)));
#pragma unroll
      for (int kk = 0; kk < 4; ++kk)
#pragma unroll
        for (int nt = 0; nt < 4; ++nt) a4[nt] = MF(ah[kk], whh[nt * 4 + kk], a4[nt]);
    }
#pragma unroll
    for (int rg = 0; rg < 4; ++rg) {
      float iv = fsig(a4[0][rg]);
      float fv = fsig(a4[1][rg]);
      float gv = ftnh(a4[2][rg]);
      float ov = fsig(a4[3][rg]);
      float c = (t == 0) ? (iv * gv) : (fv * c_st[rg] + iv * gv);
      c_st[rg] = c;
      hn[rg] = ov * ftnh(c);
    }
    if (t < 5) {
#pragma unroll
      for (int rg = 0; rg < 4; ++rg) {
        int rr = r0 + rg;
        sHb[(t & 1) * 2048 + rr * 128 + (hcol ^ ((rr & 7) << 3))] = f2bf(hn[rg]);
      }
      __syncthreads();
    } else {
#pragma unroll
      for (int rg = 0; rg < 4; ++rg)
        if (nn[rg] < cnt)
          hdst[((size_t)d * cnt + nn[rg]) * 128 + hcol] = f2bf(hn[rg]);
    }
  }
}

__global__ __launch_bounds__(512) void scan6_k(
    const int* __restrict__ xlab, const ushort* __restrict__ gxv,
    const ushort* __restrict__ h7, const ushort* __restrict__ wihrep,
    const ushort* __restrict__ whhrep, const ushort* __restrict__ linrep,
    const float* __restrict__ linb, const float* __restrict__ bihf,
    const float* __restrict__ bhhf, const float* __restrict__ bihb,
    const float* __restrict__ bhhb, ushort* __restrict__ h6) {
  __shared__ __align__(16) ushort sG[32768];
  __shared__ __align__(16) ushort sH[2][2048];
  __shared__ __align__(16) ushort sT[2048];
  scan_embed(blockIdx.x, blockIdx.y, 4096, xlab, gxv, h7, wihrep, whhrep,
             linrep, linb, bihf, bhhf, bihb, bhhb, h6, sG, &sH[0][0], sT);
}

__device__ __forceinline__ void gsync(unsigned* cnt, unsigned target) {
  __syncthreads();
  if (threadIdx.x == 0) {
    __builtin_amdgcn_fence(__ATOMIC_RELEASE, "agent");
    __hip_atomic_fetch_add(cnt, 1u, __ATOMIC_RELAXED, __HIP_MEMORY_SCOPE_AGENT);
    while (__hip_atomic_load(cnt, __ATOMIC_RELAXED, __HIP_MEMORY_SCOPE_AGENT) <
           target)
      __builtin_amdgcn_s_sleep(2);
    __builtin_amdgcn_fence(__ATOMIC_ACQUIRE, "agent");
  }
  __syncthreads();
}

// Levels 5..0 + final head, one kernel. Grid 128 blocks (co-resident on 256 CUs).
__global__ __launch_bounds__(512) void coop_tail(
    const int* __restrict__ labels, const ushort* __restrict__ gxv,
    ushort* __restrict__ hpool, const ushort* __restrict__ wihrep,
    const ushort* __restrict__ whhrep, const ushort* __restrict__ linrep,
    const float* __restrict__ linb, const float* __restrict__ bihf,
    const float* __restrict__ bhhf, const float* __restrict__ bihb,
    const float* __restrict__ bhhb, float* __restrict__ outp,
    unsigned* __restrict__ cnt) {
  __shared__ __align__(16) ushort sG[32768];
  __shared__ __align__(16) ushort sH[2][2048];
  __shared__ __align__(16) ushort sT[2048];
  const int cnts[6] = {1024, 256, 64, 16, 4, 1};
  const int xoffs[6] = {341, 85, 21, 5, 1, 0};
  const unsigned srcoff[6] = {4194304u, 5242880u, 5505024u, 5570560u, 5586944u,
                              5591040u};
  const unsigned dstoff[6] = {5242880u, 5505024u, 5570560u, 5586944u, 5591040u,
                              5592064u};
  for (int p = 0; p < 6; ++p) {
    const int c = cnts[p];
    const int ntasks = 2 * ((c + 15) >> 4);
    for (int task = blockIdx.x; task < ntasks; task += gridDim.x)
      scan_embed(task >> 1, task & 1, c, labels + xoffs[p], gxv,
                 hpool + srcoff[p], wihrep, whhrep, linrep, linb, bihf, bhhf,
                 bihb, bhhb, hpool + dstoff[p], sG, &sH[0][0], sT);
    gsync(cnt, (unsigned)(p + 1) * gridDim.x);
  }
  if (blockIdx.x == 0) {
    const int tid = threadIdx.x;
    const int w = tid >> 6, l = tid & 63, hlo = l & 15, lg = l >> 4;
    const ushort* h0 = hpool + 5592064u;
    const float lb = linb[w * 16 + hlo];
    f32x4 hac = {lb, lb, lb, lb};
#pragma unroll
    for (int kk = 0; kk < 8; ++kk) {
      bf16x8 lf = *(const bf16x8*)(linrep + w * 4096 + kk * 512 + l * 8);
      bf16x8 af =
          *(const bf16x8*)(h0 + (size_t)(kk >> 2) * 128 + (kk & 3) * 32 + lg * 8);
      hac = MF(af, lf, hac);
    }
    if (lg == 0) outp[w * 16 + hlo] = ftnh(hac[0]);
  }
}

extern "C" void kernel_launch(void* const* d_in, const int* in_sizes, int n_in,
                              void* d_out, int out_size, void* d_ws, size_t ws_size,
                              hipStream_t stream) {
  const int* labels = (const int*)d_in[0];
  const float* emb = (const float*)d_in[1];
  const float* w_ih_f = (const float*)d_in[2];
  const float* w_hh_f = (const float*)d_in[3];
  const float* b_ih_f = (const float*)d_in[4];
  const float* b_hh_f = (const float*)d_in[5];
  const float* w_ih_b = (const float*)d_in[6];
  const float* w_hh_b = (const float*)d_in[7];
  const float* b_ih_b = (const float*)d_in[8];
  const float* b_hh_b = (const float*)d_in[9];
  const float* lin_w = (const float*)d_in[10];
  const float* lin_b = (const float*)d_in[11];
  float* out = (float*)d_out;

  unsigned* cnt = (unsigned*)d_ws;
  ushort* W = (ushort*)d_ws;
  ushort* gxv = W + 512;               // 1024*1024
  ushort* gcv = gxv + 1048576;         // 1024*1024
  ushort* hpool = gcv + 1048576;       // 5592320 (h7..h0)
  ushort* hL = hpool + 5592320;        // 2*1024*128
  ushort* wall = hL + 262144;          // 425984
  ushort* whhrep = wall;
  ushort* wihrep = wall + 131072;
  ushort* linrep = wall + 262144;
  ushort* emb_bf = wall + 294912;
  ushort* h7 = hpool;                  // cap 16384
  ushort* h6 = hpool + 4194304;        // cap 4096

  hipMemsetAsync(cnt, 0, 4, stream);
  repack_all2<<<1664, 256, 0, stream>>>(w_ih_f, w_hh_f, w_ih_b, w_hh_b, emb,
                                        lin_w, wall);
  gate_vocab<<<64, 512, 0, stream>>>(emb_bf, wihrep, gxv);
  leaf_scan<<<dim3(64, 2), 512, 0, stream>>>(gxv, whhrep, b_ih_f, b_hh_f,
                                             b_ih_b, b_hh_b, hL);
  leaf_fin<<<64, 512, 0, stream>>>(hL, linrep, lin_b, wihrep, gcv);
  scan7_k<<<dim3(1024, 2), 512, 0, stream>>>(labels, gxv, gcv, whhrep, b_ih_f,
                                             b_hh_f, b_ih_b, b_hh_b, h7);
  scan6_k<<<dim3(256, 2), 512, 0, stream>>>(labels + 1365, gxv, h7, wihrep,
                                            whhrep, linrep, lin_b, b_ih_f,
                                            b_hh_f, b_ih_b, b_hh_b, h6);
  coop_tail<<<128, 512, 0, stream>>>(labels, gxv, hpool, wihrep, whhrep, linrep,
                                     lin_b, b_ih_f, b_hh_f, b_ih_b, b_hh_b, out,
                                     cnt);
}